// Round 2
// baseline (234.395 us; speedup 1.0000x reference)
//
#include <hip/hip_runtime.h>

// TELIF: temporal-encoding LIF neuron scan.
// tx: [T, B, N] fp32, TE: [N, T] fp32, out ty: [T, B, N] fp32 (0/1 spikes).
// T=512, B=64, N=1024. One thread per (b,n) sequence; sequential over t.
// Grid = 65536 threads = 4 waves/CU (1 wave/SIMD) — occupancy is grid-capped,
// so __launch_bounds__(256, 1) to unlock the full VGPR file (R1: default
// occupancy target spilled the prefetch buffers to scratch -> 232 us).
// Depth-2 software pipeline: 2 chunks (32 scalar tx loads, 8 KB/wave) in
// flight while computing, covering ~900-cycle HBM latency.

#define T_STEPS 512
#define BATCH   64
#define NNEUR   1024
#define BN      (BATCH * NNEUR)
#define UC      16

__global__ __launch_bounds__(256, 1) void telif_kernel(
    const float* __restrict__ tx, const float* __restrict__ TE,
    float* __restrict__ out)
{
    // Hard (v > th) threshold is validated against numpy fp32: forbid FMA
    // contraction and replicate the reference's exact op tree.
#pragma clang fp contract(off)

    const int flat = blockIdx.x * 256 + threadIdx.x;   // b*N + n
    const int n = flat & (NNEUR - 1);

    const float* txp  = tx + flat;        // stride BN along t, coalesced across lanes
    const float* tep  = TE + n * T_STEPS; // contiguous along t per thread
    float*       outp = out + flat;

    float v  = 0.0f;   // REST
    float y  = 0.0f;
    float th = 0.3f;   // THRESHOLD

    float x0[UC], e0[UC], x1[UC], e1[UC], x2[UC], e2[UC], x3[UC], e3[UC];

    auto prefetch = [&](int tb, float (&x)[UC], float (&e)[UC]) {
        if (tb >= T_STEPS) return;          // wave-uniform guard (tail)
#pragma unroll
        for (int u = 0; u < UC; ++u)
            x[u] = __builtin_nontemporal_load(txp + (size_t)(tb + u) * BN);
#pragma unroll
        for (int u = 0; u < UC; u += 4) {
            float4 f = *reinterpret_cast<const float4*>(tep + tb + u);
            e[u] = f.x; e[u + 1] = f.y; e[u + 2] = f.z; e[u + 3] = f.w;
        }
    };

    auto compute = [&](int t, float (&x)[UC], float (&e)[UC]) {
        // Exact reference op order:
        //   th = th + v*te - (th - THRESHOLD)*BETA
        //   v  = v*DECAY*(1-y) + x
        //   y  = (v > th)
#pragma unroll
        for (int u = 0; u < UC; ++u) {
            float a    = v * e[u];
            float bsum = th + a;
            float c    = th - 0.3f;
            float d    = c * 0.02f;
            th = bsum - d;
            float ee = v * 0.2f;
            float f1 = 1.0f - y;
            float g  = ee * f1;
            v = g + x[u];
            y = (v > th) ? 1.0f : 0.0f;
            __builtin_nontemporal_store(y, outp + (size_t)(t + u) * BN);
        }
    };

    prefetch(0,  x0, e0);
    prefetch(16, x1, e1);
#pragma unroll 1
    for (int t = 0; t < T_STEPS; t += 64) {
        prefetch(t + 32, x2, e2);
        prefetch(t + 48, x3, e3);
        __builtin_amdgcn_sched_barrier(0);   // pin: loads issue before compute
        compute(t,      x0, e0);
        compute(t + 16, x1, e1);
        prefetch(t + 64, x0, e0);
        prefetch(t + 80, x1, e1);
        __builtin_amdgcn_sched_barrier(0);
        compute(t + 32, x2, e2);
        compute(t + 48, x3, e3);
    }
}

extern "C" void kernel_launch(void* const* d_in, const int* in_sizes, int n_in,
                              void* d_out, int out_size, void* d_ws, size_t ws_size,
                              hipStream_t stream) {
    const float* tx = (const float*)d_in[0];  // [T, B, N]
    const float* TE = (const float*)d_in[1];  // [N, T]
    float* out = (float*)d_out;               // [T, B, N]
    telif_kernel<<<BN / 256, 256, 0, stream>>>(tx, TE, out);
}